// Round 13
// baseline (589.000 us; speedup 1.0000x reference)
//
#include <hip/hip_runtime.h>
#include <hip/hip_bf16.h>
#include <cstdint>

#define HIDDEN 4096
#define NH 32
#define NKV 8
#define HD 128
#define SEQ 2048
#define BSZ 2
#define QKVN 6144          // fused QKV projection width
#define QKVLD 6144         // row stride of fused QKV buffer

using bf16x8 = __attribute__((ext_vector_type(8))) short;
using f32x4  = __attribute__((ext_vector_type(4))) float;
using f32x16 = __attribute__((ext_vector_type(16))) float;

__device__ __forceinline__ ushort f2bf(float f) {
  union { float f; uint32_t u; } v; v.f = f;
  uint32_t r = (v.u + 0x7FFFu + ((v.u >> 16) & 1u)) >> 16;  // RNE
  return (ushort)r;
}
__device__ __forceinline__ float bf2f(ushort s) {
  union { uint32_t u; float f; } v; v.u = ((uint32_t)s) << 16;
  return v.f;
}

__device__ __forceinline__ uint32_t cvtpk(float lo, float hi) {
  uint32_t r;
  asm("v_cvt_pk_bf16_f32 %0, %1, %2" : "=v"(r) : "v"(lo), "v"(hi));
  return r;
}
__device__ __forceinline__ void pl32swap(uint32_t& a, uint32_t& b) {
  asm("v_permlane32_swap_b32 %0, %1" : "+v"(a), "+v"(b));
}

__device__ __forceinline__ void gload_lds16(const void* g, void* l) {
  __builtin_amdgcn_global_load_lds(
      (const __attribute__((address_space(1))) void*)g,
      (__attribute__((address_space(3))) void*)l, 16, 0, 0);
}

// ---------------------------------------------------------------------------
// fp32 -> bf16 elementwise convert (vectorized, 8 elems/thread)
// ---------------------------------------------------------------------------
__global__ __launch_bounds__(256)
void cvt_bf16_kernel(const float* __restrict__ X, ushort* __restrict__ Xb, int n8) {
  int t = blockIdx.x * 256 + threadIdx.x;
  if (t >= n8) return;
  size_t i = (size_t)t * 8;
  float4 a = *(const float4*)(X + i);
  float4 b = *(const float4*)(X + i + 4);
  uint4 p;
  p.x = (uint)f2bf(a.x) | ((uint)f2bf(a.y) << 16);
  p.y = (uint)f2bf(a.z) | ((uint)f2bf(a.w) << 16);
  p.z = (uint)f2bf(b.x) | ((uint)f2bf(b.y) << 16);
  p.w = (uint)f2bf(b.z) | ((uint)f2bf(b.w) << 16);
  *(uint4*)(Xb + i) = p;
}

// ---------------------------------------------------------------------------
// All 4 weight transposes in ONE launch. Zones: Wq(4096 blk) Wk(1024)
// Wv(1024) Wo(4096). 64x64 tile, 16B/lane both sides. K=4096 for all.
// ---------------------------------------------------------------------------
__global__ __launch_bounds__(256)
void transpose_all_kernel(const float* __restrict__ Wq, const float* __restrict__ Wk,
                          const float* __restrict__ Wv, const float* __restrict__ Wo,
                          ushort* __restrict__ BTqkv, ushort* __restrict__ WoT) {
  __shared__ ushort tile[64][72];
  const int id = blockIdx.x;
  const float* W; ushort* WT; int N, rel;
  if (id < 4096)      { W = Wq; WT = BTqkv;                          N = 4096; rel = id; }
  else if (id < 5120) { W = Wk; WT = BTqkv + (size_t)4096 * 4096;    N = 1024; rel = id - 4096; }
  else if (id < 6144) { W = Wv; WT = BTqkv + (size_t)5120 * 4096;    N = 1024; rel = id - 5120; }
  else                { W = Wo; WT = WoT;                            N = 4096; rel = id - 6144; }
  const int K = 4096;
  const int nb = N >> 6;
  const int n0 = (rel % nb) * 64, k0 = (rel / nb) * 64;

  const int tr = threadIdx.x >> 4;
  const int tc = (threadIdx.x & 15) * 4;
#pragma unroll
  for (int i = 0; i < 4; ++i) {
    const int k = tr + i * 16;
    float4 v = *(const float4*)(W + (size_t)(k0 + k) * N + n0 + tc);
    ushort4 u;
    u.x = f2bf(v.x); u.y = f2bf(v.y); u.z = f2bf(v.z); u.w = f2bf(v.w);
    *(ushort4*)&tile[k][tc] = u;
  }
  __syncthreads();
  const int nr = threadIdx.x >> 3;
  const int kc = (threadIdx.x & 7) * 8;
#pragma unroll
  for (int i = 0; i < 2; ++i) {
    const int n = nr + i * 32;
    bf16x8 o;
#pragma unroll
    for (int j = 0; j < 8; ++j) o[j] = tile[kc + j][n];
    *(bf16x8*)(WT + (size_t)(n0 + n) * K + k0 + kc) = o;
  }
}

// ---------------------------------------------------------------------------
// V part of QKV -> per-head transposed VtG[(b*NKV+kh)][d=128][SEQ] (bf16).
// ---------------------------------------------------------------------------
__global__ __launch_bounds__(256)
void transpose_v_kernel(const ushort* __restrict__ Vsrc, ushort* __restrict__ VtG) {
  __shared__ ushort tile[64][72];
  const int slice = blockIdx.z;
  const int b = slice >> 3, kh = slice & 7;
  const int s0 = blockIdx.x * 64, d0 = blockIdx.y * 64;
  const ushort* src = Vsrc + ((size_t)(b * SEQ) + s0) * QKVLD + kh * HD + d0;
  const int sr = threadIdx.x >> 3;
  const int dc = (threadIdx.x & 7) * 8;
#pragma unroll
  for (int i = 0; i < 2; ++i) {
    const int s = sr + i * 32;
    *(bf16x8*)&tile[s][dc] = *(const bf16x8*)(src + (size_t)s * QKVLD + dc);
  }
  __syncthreads();
  ushort* dst = VtG + ((size_t)slice * HD + d0) * SEQ + s0;
  const int dr = threadIdx.x >> 3;
  const int sc = (threadIdx.x & 7) * 8;
#pragma unroll
  for (int i = 0; i < 2; ++i) {
    const int d = dr + i * 32;
    bf16x8 o;
#pragma unroll
    for (int j = 0; j < 8; ++j) o[j] = tile[sc + j][d];
    *(bf16x8*)(dst + (size_t)d * SEQ + sc) = o;
  }
}

// ---------------------------------------------------------------------------
// QKV GEMM: 256x192 tile, 512 blocks (round-11 verified, ~207 us). UNCHANGED.
// ---------------------------------------------------------------------------
__global__ __launch_bounds__(512, 2)
void gemmqkv_kernel(const ushort* __restrict__ A, const ushort* __restrict__ BT,
                    ushort* __restrict__ Cp, int M, int N, int K) {
  extern __shared__ ushort lds[];   // 112 KB
  const int tid = threadIdx.x, lane = tid & 63, wave = tid >> 6;
  const int l15 = lane & 15, l4 = lane >> 4;
  const int wr = wave >> 2, wc = wave & 3;

  const int mt = M >> 8, ntile = N / 192, nwg = mt * ntile;
  const int swq = nwg >> 3, swr = nwg & 7;
  const int xcd = blockIdx.x & 7, lo = blockIdx.x >> 3;
  const int wg = (xcd < swr ? xcd * (swq + 1) : swr * (swq + 1) + (xcd - swr) * swq) + lo;
  const int m0 = (wg % mt) << 8;
  const int n0 = (wg / mt) * 192;

  ushort* LA[2][2];
  ushort* LB[2][2];
#pragma unroll
  for (int b_ = 0; b_ < 2; ++b_)
#pragma unroll
    for (int s_ = 0; s_ < 2; ++s_) {
      LA[b_][s_] = lds + (b_ * 2 + s_) * 8192;
      LB[b_][s_] = lds + 32768 + (b_ * 2 + s_) * 6144;
    }

  const ushort* Abase = A + (size_t)m0 * K;
  const ushort* Bbase = BT + (size_t)n0 * K;

  const int srow0 = tid >> 2;
  const int scol8 = (((tid & 3) ^ ((srow0 >> 1) & 3)) << 3);
  const int bs1 = tid;
  const int brow1 = bs1 >> 2;
  const int bcol1 = (((bs1 & 3) ^ ((bs1 >> 3) & 3)) << 3);
  const int bs2 = 512 + wave * 32 + (lane & 31);
  const int brow2 = bs2 >> 2;
  const int bcol2 = (((bs2 & 3) ^ ((bs2 >> 3) & 3)) << 3);

  const int swb  = (l4 ^ ((l15 >> 1) & 3)) << 3;
  const int aoff = (wr * 128 + l15) * 32 + swb;
  const int boff = (wc * 48 + l15) * 32 + swb;

  f32x4 acc[8][3] = {};
  bf16x8 a[4];
  bf16x8 b[3];

#define STAGE_EV(buf, ks, kt)                                                  \
  do {                                                                         \
    const size_t gc_ = (size_t)(kt) * 64 + (ks) * 32;                          \
    gload_lds16(Abase + (size_t)srow0 * K + gc_ + scol8,                       \
                &LA[buf][ks][tid * 8]);                                        \
    gload_lds16(Bbase + (size_t)brow1 * K + gc_ + bcol1,                       \
                &LB[buf][ks][tid * 8]);                                        \
  } while (0)

#define STAGE_OD(buf, ks, kt)                                                  \
  do {                                                                         \
    const size_t gc_ = (size_t)(kt) * 64 + (ks) * 32;                          \
    gload_lds16(Abase + (size_t)(128 + srow0) * K + gc_ + scol8,               \
                &LA[buf][ks][(512 + tid) * 8]);                                \
    if ((lane & 32) == 0)                                                      \
      gload_lds16(Bbase + (size_t)brow2 * K + gc_ + bcol2,                     \
                  &LB[buf][ks][(512 + wave * 32 + (lane & 31)) * 8]);          \
  } while (0)

#define MFMA_ __builtin_amdgcn_mfma_f32_16x16x32_bf16

#define PHASE_EVEN(buf, ks, sb, sk, skt)                                       \
  {                                                                            \
    _Pragma("unroll") for (int m_ = 0; m_ < 4; ++m_)                           \
      a[m_] = *(const bf16x8*)&LA[buf][ks][aoff + m_ * 512];                   \
    _Pragma("unroll") for (int n_ = 0; n_ < 3; ++n_)                           \
      b[n_] = *(const bf16x8*)&LB[buf][ks][boff + n_ * 512];                   \
    STAGE_EV(sb, sk, skt);                                                     \
    asm volatile("s_barrier" ::: "memory");                                    \
    __builtin_amdgcn_s_setprio(1);                                             \
    _Pragma("unroll") for (int m_ = 0; m_ < 4; ++m_)                           \
      _Pragma("unroll") for (int n_ = 0; n_ < 3; ++n_)                         \
        acc[m_][n_] = MFMA_(a[m_], b[n_], acc[m_][n_], 0, 0, 0);               \
    __builtin_amdgcn_s_setprio(0);                                             \
    asm volatile("s_barrier" ::: "memory");                                    \
  }

#define PHASE_ODD(buf, ks, sb, sk, skt)                                        \
  {                                                                            \
    _Pragma("unroll") for (int m_ = 0; m_ < 4; ++m_)                           \
      a[m_] = *(const bf16x8*)&LA[buf][ks][aoff + (4 + m_) * 512];             \
    STAGE_OD(sb, sk, skt);                                                     \
    asm volatile("s_barrier" ::: "memory");                                    \
    __builtin_amdgcn_s_setprio(1);                                             \
    _Pragma("unroll") for (int m_ = 0; m_ < 4; ++m_)                           \
      _Pragma("unroll") for (int n_ = 0; n_ < 3; ++n_)                         \
        acc[4 + m_][n_] = MFMA_(a[m_], b[n_], acc[4 + m_][n_], 0, 0, 0);       \
    __builtin_amdgcn_s_setprio(0);                                             \
    asm volatile("s_waitcnt vmcnt(8)");                                        \
    asm volatile("s_barrier" ::: "memory");                                    \
  }

  const int NT = K >> 6;

  STAGE_EV(0, 0, 0); STAGE_OD(0, 0, 0);
  STAGE_EV(0, 1, 0); STAGE_OD(0, 1, 0);
  STAGE_EV(1, 0, 1); STAGE_OD(1, 0, 1);
  asm volatile("s_waitcnt vmcnt(8)");
  asm volatile("s_barrier" ::: "memory");

  for (int i = 0; i < (NT >> 1); ++i) {
    const int kt0 = 2 * i;
    const int ktA = (kt0 + 2 < NT) ? kt0 + 2 : NT - 1;
    const int ktB = (kt0 + 3 < NT) ? kt0 + 3 : NT - 1;
    PHASE_EVEN(0, 0, 1, 1, kt0 + 1)
    PHASE_ODD (0, 0, 1, 1, kt0 + 1)
    PHASE_EVEN(0, 1, 0, 0, ktA)
    PHASE_ODD (0, 1, 0, 0, ktA)
    PHASE_EVEN(1, 0, 0, 1, ktA)
    PHASE_ODD (1, 0, 0, 1, ktA)
    PHASE_EVEN(1, 1, 1, 0, ktB)
    PHASE_ODD (1, 1, 1, 0, ktB)
  }
#undef PHASE_EVEN
#undef PHASE_ODD
#undef STAGE_EV
#undef STAGE_OD

  const int crow0 = m0 + wr * 128 + l4 * 4;
  const int ccol0 = n0 + wc * 48 + l15;
#pragma unroll
  for (int m_ = 0; m_ < 8; ++m_)
#pragma unroll
    for (int n_ = 0; n_ < 3; ++n_)
#pragma unroll
      for (int r_ = 0; r_ < 4; ++r_) {
        const size_t row = crow0 + m_ * 16 + r_;
        const int col = ccol0 + n_ * 16;
        Cp[row * N + col] = f2bf(acc[m_][n_][r_]);
      }
}

// ---------------------------------------------------------------------------
// O-projection GEMM: 128x256 tile -> 32x16 = 512 blocks = 2/CU (fill fix,
// same method as R11's QKV retile). 8 waves (2Mx4N), wave owns 64x64
// (4m x 4n frags, acc 64 regs). Ledger: 3 gloads/phase-pair (A 8KB = 1 call,
// B 16KB = 2 calls), prologue 9, vmcnt(6) at odd-phase ends. Same proven
// XOR swizzle (all fragment row-bases = 0 mod 8). LDS 96 KB.
// ---------------------------------------------------------------------------
__global__ __launch_bounds__(512, 2)
void gemmop_kernel(const ushort* __restrict__ A, const ushort* __restrict__ BT,
                   float* __restrict__ Cp, int M, int N, int K) {
  extern __shared__ ushort lds[];   // 96 KB
  const int tid = threadIdx.x, lane = tid & 63, wave = tid >> 6;
  const int l15 = lane & 15, l4 = lane >> 4;
  const int wr = wave >> 2, wc = wave & 3;

  const int mt = M >> 7, nt = N >> 8, nwg = mt * nt;   // 32 x 16 = 512
  const int swq = nwg >> 3, swr = nwg & 7;
  const int xcd = blockIdx.x & 7, lo = blockIdx.x >> 3;
  const int wg = (xcd < swr ? xcd * (swq + 1) : swr * (swq + 1) + (xcd - swr) * swq) + lo;
  const int m0 = (wg % mt) << 7;
  const int n0 = (wg / mt) << 8;

  // LDS: A 4 x 4096 ushorts (8KB), B 4 x 8192 ushorts (16KB)
  ushort* LA[2][2];
  ushort* LB[2][2];
#pragma unroll
  for (int b_ = 0; b_ < 2; ++b_)
#pragma unroll
    for (int s_ = 0; s_ < 2; ++s_) {
      LA[b_][s_] = lds + (b_ * 2 + s_) * 4096;
      LB[b_][s_] = lds + 16384 + (b_ * 2 + s_) * 8192;
    }

  const ushort* Abase = A + (size_t)m0 * K;
  const ushort* Bbase = BT + (size_t)n0 * K;

  // A staging: slot = tid; row = tid>>2 (0..127)
  const int arow = tid >> 2;
  const int acol = (((tid & 3) ^ ((arow >> 1) & 3)) << 3);
  // B staging: call p in {0,1}: slot = p*512 + tid; row = slot>>2 (0..255)
  const int brow0 = tid >> 2;
  const int bcol0 = (((tid & 3) ^ ((brow0 >> 1) & 3)) << 3);
  const int bs1 = 512 + tid;
  const int brow1 = bs1 >> 2;
  const int bcol1 = (((bs1 & 3) ^ ((brow1 >> 1) & 3)) << 3);

  // read-side swizzle (proven algebra)
  const int swb  = (l4 ^ ((l15 >> 1) & 3)) << 3;
  const int aoff = (wr * 64 + l15) * 32 + swb;
  const int boff = (wc * 64 + l15) * 32 + swb;

  f32x4 acc[4][4] = {};
  bf16x8 a[2];
  bf16x8 b[4];

#define OSTAGE_EV(buf, ks, kt)                                                 \
  do {                                                                         \
    const size_t gc_ = (size_t)(kt) * 64 + (ks) * 32;                          \
    gload_lds16(Abase + (size_t)arow * K + gc_ + acol,  &LA[buf][ks][tid * 8]);\
    gload_lds16(Bbase + (size_t)brow0 * K + gc_ + bcol0, &LB[buf][ks][tid * 8]);\
  } while (0)

#define OSTAGE_OD(buf, ks, kt)                                                 \
  do {                                                                         \
    const size_t gc_ = (size_t)(kt) * 64 + (ks) * 32;                          \
    gload_lds16(Bbase + (size_t)brow1 * K + gc_ + bcol1,                       \
                &LB[buf][ks][(512 + tid) * 8]);                                \
  } while (0)

#define MFMA_ __builtin_amdgcn_mfma_f32_16x16x32_bf16

#define OPHASE_EVEN(buf, ks, sb, sk, skt)                                      \
  {                                                                            \
    _Pragma("unroll") for (int m_ = 0; m_ < 2; ++m_)                           \
      a[m_] = *(const bf16x8*)&LA[buf][ks][aoff + m_ * 512];                   \
    _Pragma("unroll") for (int n_ = 0; n_ < 4; ++n_)                           \
      b[n_] = *(const bf16x8*)&LB[buf][ks][boff + n_ * 512];                   \
    OSTAGE_EV(sb, sk, skt);                                                    \
    asm volatile("s_barrier" ::: "memory");                                    \
    __builtin_amdgcn_s_setprio(1);                                             \
    _Pragma("unroll") for (int m_ = 0; m_ < 2; ++m_)                           \
      _Pragma("unroll") for (int n_ = 0; n_ < 4; ++n_)                         \
        acc[m_][n_] = MFMA_(a[m_], b[n_], acc[m_][n_], 0, 0, 0);               \
    __builtin_amdgcn_s_setprio(0);                                             \
    asm volatile("s_barrier" ::: "memory");                                    \
  }

#define OPHASE_ODD(buf, ks, sb, sk, skt)                                       \
  {                                                                            \
    _Pragma("unroll") for (int m_ = 0; m_ < 2; ++m_)                           \
      a[m_] = *(const bf16x8*)&LA[buf][ks][aoff + (2 + m_) * 512];             \
    OSTAGE_OD(sb, sk, skt);                                                    \
    asm volatile("s_barrier" ::: "memory");                                    \
    __builtin_amdgcn_s_setprio(1);                                             \
    _Pragma("unroll") for (int m_ = 0; m_ < 2; ++m_)                           \
      _Pragma("unroll") for (int n_ = 0; n_ < 4; ++n_)                         \
        acc[2 + m_][n_] = MFMA_(a[m_], b[n_], acc[2 + m_][n_], 0, 0, 0);       \
    __builtin_amdgcn_s_setprio(0);                                             \
    asm volatile("s_waitcnt vmcnt(6)");                                        \
    asm volatile("s_barrier" ::: "memory");                                    \
  }

  const int NT = K >> 6;

  // prologue: 3 kslices x 3 gloads = 9 outstanding; first kslice = oldest 3
  OSTAGE_EV(0, 0, 0); OSTAGE_OD(0, 0, 0);
  OSTAGE_EV(0, 1, 0); OSTAGE_OD(0, 1, 0);
  OSTAGE_EV(1, 0, 1); OSTAGE_OD(1, 0, 1);
  asm volatile("s_waitcnt vmcnt(6)");
  asm volatile("s_barrier" ::: "memory");

  for (int i = 0; i < (NT >> 1); ++i) {
    const int kt0 = 2 * i;
    const int ktA = (kt0 + 2 < NT) ? kt0 + 2 : NT - 1;
    const int ktB = (kt0 + 3 < NT) ? kt0 + 3 : NT - 1;
    OPHASE_EVEN(0, 0, 1, 1, kt0 + 1)
    OPHASE_ODD (0, 0, 1, 1, kt0 + 1)
    OPHASE_EVEN(0, 1, 0, 0, ktA)
    OPHASE_ODD (0, 1, 0, 0, ktA)
    OPHASE_EVEN(1, 0, 0, 1, ktA)
    OPHASE_ODD (1, 0, 0, 1, ktA)
    OPHASE_EVEN(1, 1, 1, 0, ktB)
    OPHASE_ODD (1, 1, 1, 0, ktB)
  }
#undef OPHASE_EVEN
#undef OPHASE_ODD
#undef OSTAGE_EV
#undef OSTAGE_OD

  const int crow0 = m0 + wr * 64 + l4 * 4;
  const int ccol0 = n0 + wc * 64 + l15;
#pragma unroll
  for (int m_ = 0; m_ < 4; ++m_)
#pragma unroll
    for (int n_ = 0; n_ < 4; ++n_)
#pragma unroll
      for (int r_ = 0; r_ < 4; ++r_) {
        const size_t row = crow0 + m_ * 16 + r_;
        const int col = ccol0 + n_ * 16;
        Cp[row * N + col] = acc[m_][n_][r_];
      }
}

// ---------------------------------------------------------------------------
// RoPE for Q and K in one launch. hp 0-31 = Q head (scaled), 32-39 = K head.
// ---------------------------------------------------------------------------
__global__ __launch_bounds__(256)
void rope_qk_kernel(ushort* qkv, const int* __restrict__ pos_ids, int total) {
  int t = blockIdx.x * 256 + threadIdx.x;
  if (t >= total) return;
  int j = t & 63;
  int rest = t >> 6;
  int hp = rest % 40;
  int bs = rest / 40;
  float pos = (float)pos_ids[bs];
  float inv = exp2f(-(float)j * (13.287712379549449f / 64.0f));
  float ang = pos * inv;
  const float osc = (hp < 32) ? 0.12751731f : 1.0f;   // Q: 1/sqrt(128)*log2e
  float c = cosf(ang) * osc, s = sinf(ang) * osc;
  const int col = (hp < 32) ? hp * HD : HIDDEN + (hp - 32) * HD;
  ushort* p = qkv + (size_t)bs * QKVLD + col + j;
  float x1 = bf2f(p[0]), x2 = bf2f(p[64]);
  p[0]  = f2bf(x1 * c - x2 * s);
  p[64] = f2bf(x2 * c + x1 * s);
}

// ---------------------------------------------------------------------------
// Flash attention, causal, GQA. 8 warps x 32 q-rows (block = 256 q x 1 head).
// Swapped QK^T (32x32x16), in-register P (cvt_pk + permlane32_swap),
// O^T = mfma(V^T, P^T), scalar softmax state per lane. K+V double-buffered,
// one barrier per tile. (Round-12 config, unchanged.)
// ---------------------------------------------------------------------------
__global__ __launch_bounds__(512)
void attn_kernel(const ushort* __restrict__ Q, const ushort* __restrict__ K0,
                 const ushort* __restrict__ VtG, ushort* __restrict__ AO) {
  __shared__ ushort Ks[2][64 * 128];    // [k][d], slot16 ^= (k&15), 2x16KB
  __shared__ ushort Vs[2][128 * 64];    // [d][k], slot8 ^= (d&7), 2x16KB

  const int bid = blockIdx.x;
  const int kh  = bid & 7;
  const int r2  = bid >> 3;
  const int qtB = 7 - (r2 & 7);         // LPT
  const int hq  = (r2 >> 3) & 3;
  const int b   = r2 >> 5;
  const int h   = kh * 4 + hq;
  const int q0b = qtB * 256;

  const int tid = threadIdx.x, lane = tid & 63, w = tid >> 6;
  const int l31 = lane & 31, hi = lane >> 5;
  const int q0w = q0b + w * 32;

  const size_t bS = (size_t)b * SEQ;
  const ushort* Kb = K0 + bS * QKVLD + kh * HD;
  const ushort* Vb = VtG + (size_t)(b * NKV + kh) * HD * SEQ;

  bf16x8 qf[8];
  {
    const ushort* qp = Q + (bS + q0w + l31) * QKVLD + h * HD + hi * 8;
#pragma unroll
    for (int ds = 0; ds < 8; ++ds) qf[ds] = *(const bf16x8*)(qp + ds * 16);
  }

  f32x16 accO[4] = {};
  float mrow = -1e30f, denom = 0.0f;

  const int nt = qtB * 4 + 4;

  const int j0 = 2 * w, j1 = 2 * w + 1;
  const int kl4 = lane >> 4, ks15 = lane & 15;
  const int vl3 = lane >> 3, vs7 = lane & 7;
  const int kswz = lane & 15;
  const int vswz = lane & 7;

#define KSTAGE(jj, bb, kk0) { const int k_ = (jj) * 4 + kl4;                   \
    gload_lds16(Kb + (size_t)((kk0) + k_) * QKVLD + ((ks15 ^ (k_ & 15)) << 3), \
                &Ks[bb][(jj) * 512 + lane * 8]); }
#define VSTAGE(jj, bb, kk0) { const int d_ = (jj) * 8 + vl3;                   \
    gload_lds16(Vb + (size_t)d_ * SEQ + (kk0) + ((vs7 ^ (d_ & 7)) << 3),       \
                &Vs[bb][(jj) * 512 + lane * 8]); }

  KSTAGE(j0, 0, 0) KSTAGE(j1, 0, 0) VSTAGE(j0, 0, 0) VSTAGE(j1, 0, 0)
  __syncthreads();

  for (int t = 0; t < nt; ++t) {
    const int k0 = t * 64;
    const int cur = t & 1;
    const bool pf = (t + 1 < nt);
    const bool skip = (k0 > q0w + 31);

    if (pf) {
      const int kn = k0 + 64;
      KSTAGE(j0, cur ^ 1, kn) KSTAGE(j1, cur ^ 1, kn)
      VSTAGE(j0, cur ^ 1, kn) VSTAGE(j1, cur ^ 1, kn)
    }

    if (!skip) {
      f32x16 s0 = {}, s1 = {};
      __builtin_amdgcn_s_setprio(1);
#pragma unroll
      for (int ds = 0; ds < 8; ++ds) {
        const int so = ((ds * 2 + hi) ^ kswz) << 3;
        bf16x8 kf0 = *(const bf16x8*)&Ks[cur][l31 * 128 + so];
        bf16x8 kf1 = *(const bf16x8*)&Ks[cur][(32 + l31) * 128 + so];
        s0 = __builtin_amdgcn_mfma_f32_32x32x16_bf16(kf0, qf[ds], s0, 0, 0, 0);
        s1 = __builtin_amdgcn_mfma_f32_32x32x16_bf16(kf1, qf[ds], s1, 0, 0, 0);
      }
      __builtin_amdgcn_s_setprio(0);

      if (k0 + 63 > q0w) {
        const int qrel = q0w + l31 - k0;
#pragma unroll
        for (int r = 0; r < 16; ++r) {
          const int kc = (r & 3) + 8 * (r >> 2) + 4 * hi;
          if (kc > qrel)      s0[r] = -1e30f;
          if (kc + 32 > qrel) s1[r] = -1e30f;
        }
      }
      float pm = s0[0];
#pragma unroll
      for (int r = 1; r < 16; ++r) pm = fmaxf(pm, s0[r]);
#pragma unroll
      for (int r = 0; r < 16; ++r) pm = fmaxf(pm, s1[r]);

      if (!__all(pm - mrow <= 8.0f)) {
        pm = fmaxf(pm, __shfl_xor(pm, 32));
        const float mn = fmaxf(mrow, pm);
        const float alpha = exp2f(mrow - mn);
        mrow = mn;
        denom *= alpha;
#pragma unroll
        for (int du = 0; du < 4; ++du)
#pragma unroll
          for (int r = 0; r < 16; ++r) accO[du][r] *= alpha;
      }
      float ssum = 0.0f;
#pragma unroll
      for (int r = 0; r < 16; ++r) { float p = exp2f(s0[r] - mrow); s0[r] = p; ssum += p; }
#pragma unroll
      for (int r = 0; r < 16; ++r) { float p = exp2f(s1[r] - mrow); s1[r] = p; ssum += p; }
      denom += ssum;

      uint32_t paw[4][4];
      {
        uint32_t p0 = cvtpk(s0[0], s0[1]),   p1 = cvtpk(s0[2], s0[3]);
        uint32_t p2 = cvtpk(s0[4], s0[5]),   p3 = cvtpk(s0[6], s0[7]);
        uint32_t p4 = cvtpk(s0[8], s0[9]),   p5 = cvtpk(s0[10], s0[11]);
        uint32_t p6 = cvtpk(s0[12], s0[13]), p7 = cvtpk(s0[14], s0[15]);
        pl32swap(p0, p2); pl32swap(p1, p3); pl32swap(p4, p6); pl32swap(p5, p7);
        paw[0][0] = p0; paw[0][1] = p1; paw[0][2] = p2; paw[0][3] = p3;
        paw[1][0] = p4; paw[1][1] = p5; paw[1][2] = p6; paw[1][3] = p7;
      }
      {
        uint32_t p0 = cvtpk(s1[0], s1[1]),   p1 = cvtpk(s1[2], s1[3]);
        uint32_t p2 = cvtpk(s1[4], s1[5]),   p3 = cvtpk(s1[6], s1[7]);
        uint32_t p4 = cvtpk(s1[8], s1[9]),   p5 = cvtpk(s1[10], s1[11]);
        uint32_t p6 = cvtpk(s1[12], s1[13]), p7 = cvtpk(s1[14], s1[15]);
        pl32swap(p0, p2); pl32swap(p1, p3); pl32swap(p4, p6); pl32swap(p5, p7);
        paw[2][0] = p0; paw[2][1] = p1; paw[2][2] = p2; paw[2][3] = p3;
        paw[3][0] = p4; paw[3][1] = p5; paw[3][2] = p6; paw[3][3] = p7;
      }

      __builtin_amdgcn_s_setprio(1);
#pragma unroll
      for (int du = 0; du < 4; ++du) {
#pragma unroll
        for (int ks = 0; ks < 4; ++ks) {
          const int so = ((ks * 2 + hi) ^ vswz) << 3;
          bf16x8 vf = *(const bf16x8*)&Vs[cur][(du * 32 + l31) * 64 + so];
          bf16x8 pb = *(const bf16x8*)&paw[ks][0];
          accO[du] = __builtin_amdgcn_mfma_f32_32x32x16_bf16(vf, pb, accO[du], 0, 0, 0);
        }
      }
      __builtin_amdgcn_s_setprio(0);
    }
    __syncthreads();
  }
#undef KSTAGE
#undef VSTAGE

  denom += __shfl_xor(denom, 32);
  const float inv = 1.0f / denom;
  ushort* op = AO + (bS + q0w + l31) * HIDDEN + h * HD + hi * 4;
#pragma unroll
  for (int du = 0; du < 4; ++du)
#pragma unroll
    for (int g = 0; g < 4; ++g) {
      uint2 u;
      u.x = cvtpk(accO[du][4 * g + 0] * inv, accO[du][4 * g + 1] * inv);
      u.y = cvtpk(accO[du][4 * g + 2] * inv, accO[du][4 * g + 3] * inv);
      *(uint2*)(op + du * 32 + g * 8) = u;
    }
}

// ---------------------------------------------------------------------------
extern "C" void kernel_launch(void* const* d_in, const int* in_sizes, int n_in,
                              void* d_out, int out_size, void* d_ws, size_t ws_size,
                              hipStream_t stream) {
  (void)in_sizes; (void)n_in; (void)out_size; (void)ws_size;
  const float* X   = (const float*)d_in[0];
  const int*   pos = (const int*)d_in[2];
  const float* Wq  = (const float*)d_in[3];
  const float* Wk  = (const float*)d_in[4];
  const float* Wv  = (const float*)d_in[5];
  const float* Wo  = (const float*)d_in[6];

  char* ws = (char*)d_ws;
  ushort* Xb    = (ushort*)(ws);                    // 33,554,432 B (aliased by AO)
  ushort* QKV   = (ushort*)(ws + 33554432);         // 50,331,648 B  [M][6144]
  ushort* BTqkv = (ushort*)(ws + 83886080);         // 50,331,648 B
  ushort* WoT   = (ushort*)(ws + 134217728);        // 33,554,432 B
  ushort* AO    = Xb;                               // X dead after QKV projection
  ushort* VtG   = BTqkv;                            // BTqkv dead after QKV GEMM

  const int M = BSZ * SEQ;  // 4096
  dim3 blk(256);

  hipFuncSetAttribute((const void*)gemmqkv_kernel,
                      hipFuncAttributeMaxDynamicSharedMemorySize, 114688);
  hipFuncSetAttribute((const void*)gemmop_kernel,
                      hipFuncAttributeMaxDynamicSharedMemorySize, 98304);

  // ---- pre-passes: X convert + all 4 weight transposes in one launch ----
  cvt_bf16_kernel<<<dim3((M * HIDDEN / 8 + 255) / 256), blk, 0, stream>>>(X, Xb, M * HIDDEN / 8);
  transpose_all_kernel<<<dim3(10240), blk, 0, stream>>>(Wq, Wk, Wv, Wo, BTqkv, WoT);

  // ---- fused QKV projection: 256x192 tiles -> 512 blocks ----
  gemmqkv_kernel<<<dim3((M / 256) * (QKVN / 192)), dim3(512), 114688, stream>>>(
      Xb, BTqkv, QKV, M, QKVN, HIDDEN);

  // ---- RoPE Q+K in one launch + V transpose ----
  rope_qk_kernel<<<dim3((M * 40 * 64) / 256), blk, 0, stream>>>(QKV, pos, M * 40 * 64);
  transpose_v_kernel<<<dim3(SEQ / 64, HD / 64, BSZ * NKV), blk, 0, stream>>>(
      QKV + HIDDEN + NKV * HD, VtG);

  // ---- flash attention ----
  attn_kernel<<<dim3(512), dim3(512), 0, stream>>>(QKV, QKV + HIDDEN, VtG, AO);

  // ---- output projection -> fp32 d_out: 128x256 tiles -> 512 blocks ----
  gemmop_kernel<<<dim3((M / 128) * (HIDDEN / 256)), dim3(512), 98304, stream>>>(
      AO, WoT, (float*)d_out, M, HIDDEN, HIDDEN);
}

// Round 14
// 568.811 us; speedup vs baseline: 1.0355x; 1.0355x over previous
//
#include <hip/hip_runtime.h>
#include <hip/hip_bf16.h>
#include <cstdint>

#define HIDDEN 4096
#define NH 32
#define NKV 8
#define HD 128
#define SEQ 2048
#define BSZ 2
#define QKVN 6144          // fused QKV projection width
#define QKVLD 6144         // row stride of fused QKV buffer

using bf16x8 = __attribute__((ext_vector_type(8))) short;
using f32x4  = __attribute__((ext_vector_type(4))) float;
using f32x16 = __attribute__((ext_vector_type(16))) float;

__device__ __forceinline__ ushort f2bf(float f) {
  union { float f; uint32_t u; } v; v.f = f;
  uint32_t r = (v.u + 0x7FFFu + ((v.u >> 16) & 1u)) >> 16;  // RNE
  return (ushort)r;
}
__device__ __forceinline__ float bf2f(ushort s) {
  union { uint32_t u; float f; } v; v.u = ((uint32_t)s) << 16;
  return v.f;
}

__device__ __forceinline__ uint32_t cvtpk(float lo, float hi) {
  uint32_t r;
  asm("v_cvt_pk_bf16_f32 %0, %1, %2" : "=v"(r) : "v"(lo), "v"(hi));
  return r;
}
__device__ __forceinline__ void pl32swap(uint32_t& a, uint32_t& b) {
  asm("v_permlane32_swap_b32 %0, %1" : "+v"(a), "+v"(b));
}

__device__ __forceinline__ void gload_lds16(const void* g, void* l) {
  __builtin_amdgcn_global_load_lds(
      (const __attribute__((address_space(1))) void*)g,
      (__attribute__((address_space(3))) void*)l, 16, 0, 0);
}

// ---------------------------------------------------------------------------
// fp32 -> bf16 elementwise convert (vectorized, 8 elems/thread)
// ---------------------------------------------------------------------------
__global__ __launch_bounds__(256)
void cvt_bf16_kernel(const float* __restrict__ X, ushort* __restrict__ Xb, int n8) {
  int t = blockIdx.x * 256 + threadIdx.x;
  if (t >= n8) return;
  size_t i = (size_t)t * 8;
  float4 a = *(const float4*)(X + i);
  float4 b = *(const float4*)(X + i + 4);
  uint4 p;
  p.x = (uint)f2bf(a.x) | ((uint)f2bf(a.y) << 16);
  p.y = (uint)f2bf(a.z) | ((uint)f2bf(a.w) << 16);
  p.z = (uint)f2bf(b.x) | ((uint)f2bf(b.y) << 16);
  p.w = (uint)f2bf(b.z) | ((uint)f2bf(b.w) << 16);
  *(uint4*)(Xb + i) = p;
}

// ---------------------------------------------------------------------------
// All 4 weight transposes in ONE launch (zones). 64x64 tile, 16B/lane.
// ---------------------------------------------------------------------------
__global__ __launch_bounds__(256)
void transpose_all_kernel(const float* __restrict__ Wq, const float* __restrict__ Wk,
                          const float* __restrict__ Wv, const float* __restrict__ Wo,
                          ushort* __restrict__ BTqkv, ushort* __restrict__ WoT) {
  __shared__ ushort tile[64][72];
  const int id = blockIdx.x;
  const float* W; ushort* WT; int N, rel;
  if (id < 4096)      { W = Wq; WT = BTqkv;                          N = 4096; rel = id; }
  else if (id < 5120) { W = Wk; WT = BTqkv + (size_t)4096 * 4096;    N = 1024; rel = id - 4096; }
  else if (id < 6144) { W = Wv; WT = BTqkv + (size_t)5120 * 4096;    N = 1024; rel = id - 5120; }
  else                { W = Wo; WT = WoT;                            N = 4096; rel = id - 6144; }
  const int K = 4096;
  const int nb = N >> 6;
  const int n0 = (rel % nb) * 64, k0 = (rel / nb) * 64;

  const int tr = threadIdx.x >> 4;
  const int tc = (threadIdx.x & 15) * 4;
#pragma unroll
  for (int i = 0; i < 4; ++i) {
    const int k = tr + i * 16;
    float4 v = *(const float4*)(W + (size_t)(k0 + k) * N + n0 + tc);
    ushort4 u;
    u.x = f2bf(v.x); u.y = f2bf(v.y); u.z = f2bf(v.z); u.w = f2bf(v.w);
    *(ushort4*)&tile[k][tc] = u;
  }
  __syncthreads();
  const int nr = threadIdx.x >> 3;
  const int kc = (threadIdx.x & 7) * 8;
#pragma unroll
  for (int i = 0; i < 2; ++i) {
    const int n = nr + i * 32;
    bf16x8 o;
#pragma unroll
    for (int j = 0; j < 8; ++j) o[j] = tile[kc + j][n];
    *(bf16x8*)(WT + (size_t)(n0 + n) * K + k0 + kc) = o;
  }
}

// ---------------------------------------------------------------------------
// V part of QKV -> per-head transposed VtG[(b*NKV+kh)][d=128][SEQ] (bf16).
// ---------------------------------------------------------------------------
__global__ __launch_bounds__(256)
void transpose_v_kernel(const ushort* __restrict__ Vsrc, ushort* __restrict__ VtG) {
  __shared__ ushort tile[64][72];
  const int slice = blockIdx.z;
  const int b = slice >> 3, kh = slice & 7;
  const int s0 = blockIdx.x * 64, d0 = blockIdx.y * 64;
  const ushort* src = Vsrc + ((size_t)(b * SEQ) + s0) * QKVLD + kh * HD + d0;
  const int sr = threadIdx.x >> 3;
  const int dc = (threadIdx.x & 7) * 8;
#pragma unroll
  for (int i = 0; i < 2; ++i) {
    const int s = sr + i * 32;
    *(bf16x8*)&tile[s][dc] = *(const bf16x8*)(src + (size_t)s * QKVLD + dc);
  }
  __syncthreads();
  ushort* dst = VtG + ((size_t)slice * HD + d0) * SEQ + s0;
  const int dr = threadIdx.x >> 3;
  const int sc = (threadIdx.x & 7) * 8;
#pragma unroll
  for (int i = 0; i < 2; ++i) {
    const int d = dr + i * 32;
    bf16x8 o;
#pragma unroll
    for (int j = 0; j < 8; ++j) o[j] = tile[sc + j][d];
    *(bf16x8*)(dst + (size_t)d * SEQ + sc) = o;
  }
}

// ---------------------------------------------------------------------------
// QKV GEMM: 256x192 tile, 512 blocks (round-11 verified, ~207 us). UNCHANGED.
// ---------------------------------------------------------------------------
__global__ __launch_bounds__(512, 2)
void gemmqkv_kernel(const ushort* __restrict__ A, const ushort* __restrict__ BT,
                    ushort* __restrict__ Cp, int M, int N, int K) {
  extern __shared__ ushort lds[];   // 112 KB
  const int tid = threadIdx.x, lane = tid & 63, wave = tid >> 6;
  const int l15 = lane & 15, l4 = lane >> 4;
  const int wr = wave >> 2, wc = wave & 3;

  const int mt = M >> 8, ntile = N / 192, nwg = mt * ntile;
  const int swq = nwg >> 3, swr = nwg & 7;
  const int xcd = blockIdx.x & 7, lo = blockIdx.x >> 3;
  const int wg = (xcd < swr ? xcd * (swq + 1) : swr * (swq + 1) + (xcd - swr) * swq) + lo;
  const int m0 = (wg % mt) << 8;
  const int n0 = (wg / mt) * 192;

  ushort* LA[2][2];
  ushort* LB[2][2];
#pragma unroll
  for (int b_ = 0; b_ < 2; ++b_)
#pragma unroll
    for (int s_ = 0; s_ < 2; ++s_) {
      LA[b_][s_] = lds + (b_ * 2 + s_) * 8192;
      LB[b_][s_] = lds + 32768 + (b_ * 2 + s_) * 6144;
    }

  const ushort* Abase = A + (size_t)m0 * K;
  const ushort* Bbase = BT + (size_t)n0 * K;

  const int srow0 = tid >> 2;
  const int scol8 = (((tid & 3) ^ ((srow0 >> 1) & 3)) << 3);
  const int bs1 = tid;
  const int brow1 = bs1 >> 2;
  const int bcol1 = (((bs1 & 3) ^ ((bs1 >> 3) & 3)) << 3);
  const int bs2 = 512 + wave * 32 + (lane & 31);
  const int brow2 = bs2 >> 2;
  const int bcol2 = (((bs2 & 3) ^ ((bs2 >> 3) & 3)) << 3);

  const int swb  = (l4 ^ ((l15 >> 1) & 3)) << 3;
  const int aoff = (wr * 128 + l15) * 32 + swb;
  const int boff = (wc * 48 + l15) * 32 + swb;

  f32x4 acc[8][3] = {};
  bf16x8 a[4];
  bf16x8 b[3];

#define STAGE_EV(buf, ks, kt)                                                  \
  do {                                                                         \
    const size_t gc_ = (size_t)(kt) * 64 + (ks) * 32;                          \
    gload_lds16(Abase + (size_t)srow0 * K + gc_ + scol8,                       \
                &LA[buf][ks][tid * 8]);                                        \
    gload_lds16(Bbase + (size_t)brow1 * K + gc_ + bcol1,                       \
                &LB[buf][ks][tid * 8]);                                        \
  } while (0)

#define STAGE_OD(buf, ks, kt)                                                  \
  do {                                                                         \
    const size_t gc_ = (size_t)(kt) * 64 + (ks) * 32;                          \
    gload_lds16(Abase + (size_t)(128 + srow0) * K + gc_ + scol8,               \
                &LA[buf][ks][(512 + tid) * 8]);                                \
    if ((lane & 32) == 0)                                                      \
      gload_lds16(Bbase + (size_t)brow2 * K + gc_ + bcol2,                     \
                  &LB[buf][ks][(512 + wave * 32 + (lane & 31)) * 8]);          \
  } while (0)

#define MFMA_ __builtin_amdgcn_mfma_f32_16x16x32_bf16

#define PHASE_EVEN(buf, ks, sb, sk, skt)                                       \
  {                                                                            \
    _Pragma("unroll") for (int m_ = 0; m_ < 4; ++m_)                           \
      a[m_] = *(const bf16x8*)&LA[buf][ks][aoff + m_ * 512];                   \
    _Pragma("unroll") for (int n_ = 0; n_ < 3; ++n_)                           \
      b[n_] = *(const bf16x8*)&LB[buf][ks][boff + n_ * 512];                   \
    STAGE_EV(sb, sk, skt);                                                     \
    asm volatile("s_barrier" ::: "memory");                                    \
    __builtin_amdgcn_s_setprio(1);                                             \
    _Pragma("unroll") for (int m_ = 0; m_ < 4; ++m_)                           \
      _Pragma("unroll") for (int n_ = 0; n_ < 3; ++n_)                         \
        acc[m_][n_] = MFMA_(a[m_], b[n_], acc[m_][n_], 0, 0, 0);               \
    __builtin_amdgcn_s_setprio(0);                                             \
    asm volatile("s_barrier" ::: "memory");                                    \
  }

#define PHASE_ODD(buf, ks, sb, sk, skt)                                        \
  {                                                                            \
    _Pragma("unroll") for (int m_ = 0; m_ < 4; ++m_)                           \
      a[m_] = *(const bf16x8*)&LA[buf][ks][aoff + (4 + m_) * 512];             \
    STAGE_OD(sb, sk, skt);                                                     \
    asm volatile("s_barrier" ::: "memory");                                    \
    __builtin_amdgcn_s_setprio(1);                                             \
    _Pragma("unroll") for (int m_ = 0; m_ < 4; ++m_)                           \
      _Pragma("unroll") for (int n_ = 0; n_ < 3; ++n_)                         \
        acc[4 + m_][n_] = MFMA_(a[m_], b[n_], acc[4 + m_][n_], 0, 0, 0);       \
    __builtin_amdgcn_s_setprio(0);                                             \
    asm volatile("s_waitcnt vmcnt(8)");                                        \
    asm volatile("s_barrier" ::: "memory");                                    \
  }

  const int NT = K >> 6;

  STAGE_EV(0, 0, 0); STAGE_OD(0, 0, 0);
  STAGE_EV(0, 1, 0); STAGE_OD(0, 1, 0);
  STAGE_EV(1, 0, 1); STAGE_OD(1, 0, 1);
  asm volatile("s_waitcnt vmcnt(8)");
  asm volatile("s_barrier" ::: "memory");

  for (int i = 0; i < (NT >> 1); ++i) {
    const int kt0 = 2 * i;
    const int ktA = (kt0 + 2 < NT) ? kt0 + 2 : NT - 1;
    const int ktB = (kt0 + 3 < NT) ? kt0 + 3 : NT - 1;
    PHASE_EVEN(0, 0, 1, 1, kt0 + 1)
    PHASE_ODD (0, 0, 1, 1, kt0 + 1)
    PHASE_EVEN(0, 1, 0, 0, ktA)
    PHASE_ODD (0, 1, 0, 0, ktA)
    PHASE_EVEN(1, 0, 0, 1, ktA)
    PHASE_ODD (1, 0, 0, 1, ktA)
    PHASE_EVEN(1, 1, 1, 0, ktB)
    PHASE_ODD (1, 1, 1, 0, ktB)
  }
#undef PHASE_EVEN
#undef PHASE_ODD
#undef STAGE_EV
#undef STAGE_OD

  const int crow0 = m0 + wr * 128 + l4 * 4;
  const int ccol0 = n0 + wc * 48 + l15;
#pragma unroll
  for (int m_ = 0; m_ < 8; ++m_)
#pragma unroll
    for (int n_ = 0; n_ < 3; ++n_)
#pragma unroll
      for (int r_ = 0; r_ < 4; ++r_) {
        const size_t row = crow0 + m_ * 16 + r_;
        const int col = ccol0 + n_ * 16;
        Cp[row * N + col] = f2bf(acc[m_][n_][r_]);
      }
}

// ---------------------------------------------------------------------------
// 256x256 8-phase GEMM — O-projection (R11-measured config, restored).
// ---------------------------------------------------------------------------
template<int OUT_BF16>
__global__ __launch_bounds__(512, 2)
void gemm8p_kernel(const ushort* __restrict__ A, const ushort* __restrict__ BT,
                   void* __restrict__ Cp, int M, int N, int K) {
  extern __shared__ ushort lds[];   // 128 KB
  const int tid = threadIdx.x, lane = tid & 63, wave = tid >> 6;
  const int l15 = lane & 15, l4 = lane >> 4;
  const int wr = wave >> 2, wc = wave & 3;

  const int mt = M >> 8, nt = N >> 8, nwg = mt * nt;
  const int swq = nwg >> 3, swr = nwg & 7;
  const int xcd = blockIdx.x & 7, lo = blockIdx.x >> 3;
  const int wg = (xcd < swr ? xcd * (swq + 1) : swr * (swq + 1) + (xcd - swr) * swq) + lo;
  const int m0 = (wg % mt) << 8;
  const int n0 = (wg / mt) << 8;

  ushort* LA[2][2];
  ushort* LB[2][2];
#pragma unroll
  for (int b_ = 0; b_ < 2; ++b_)
#pragma unroll
    for (int s_ = 0; s_ < 2; ++s_) {
      LA[b_][s_] = lds + ((b_ * 2 + 0) * 2 + s_) * 8192;
      LB[b_][s_] = lds + ((b_ * 2 + 1) * 2 + s_) * 8192;
    }

  const ushort* Abase = A + (size_t)m0 * K;
  const ushort* Bbase = BT + (size_t)n0 * K;

  const int srow0 = tid >> 2;
  const int scol8 = (((tid & 3) ^ ((srow0 >> 1) & 3)) << 3);

  const int swb  = (l4 ^ ((l15 >> 1) & 3)) << 3;
  const int aoff = (wr * 128 + l15) * 32 + swb;
  const int boff = (wc * 64 + l15) * 32 + swb;

  f32x4 acc[8][4] = {};
  bf16x8 a[8];
  bf16x8 b[4];

#define STAGE(buf, ks, kt, part)                                              \
  do {                                                                        \
    const size_t gc_ = (size_t)(kt) * 64 + (ks) * 32 + scol8;                 \
    const int rw_ = srow0 + (part) * 128;                                     \
    const int dst_ = ((part) * 512 + tid) * 8;                                \
    gload_lds16(Abase + (size_t)rw_ * K + gc_, &LA[buf][ks][dst_]);           \
    gload_lds16(Bbase + (size_t)rw_ * K + gc_, &LB[buf][ks][dst_]);           \
  } while (0)

#define MFMA_ __builtin_amdgcn_mfma_f32_16x16x32_bf16

#define PHASE_EVEN(buf, ks, sb, sk, skt)                                      \
  {                                                                           \
    _Pragma("unroll") for (int m_ = 0; m_ < 8; ++m_)                          \
      a[m_] = *(const bf16x8*)&LA[buf][ks][aoff + m_ * 512];                  \
    b[0] = *(const bf16x8*)&LB[buf][ks][boff];                                \
    b[1] = *(const bf16x8*)&LB[buf][ks][boff + 512];                          \
    STAGE(sb, sk, skt, 0);                                                    \
    asm volatile("s_barrier" ::: "memory");                                   \
    __builtin_amdgcn_s_setprio(1);                                            \
    _Pragma("unroll") for (int m_ = 0; m_ < 8; ++m_) {                        \
      acc[m_][0] = MFMA_(a[m_], b[0], acc[m_][0], 0, 0, 0);                   \
      acc[m_][1] = MFMA_(a[m_], b[1], acc[m_][1], 0, 0, 0);                   \
    }                                                                         \
    __builtin_amdgcn_s_setprio(0);                                            \
    asm volatile("s_barrier" ::: "memory");                                   \
  }

#define PHASE_ODD(buf, ks, sb, sk, skt)                                       \
  {                                                                           \
    b[2] = *(const bf16x8*)&LB[buf][ks][boff + 1024];                         \
    b[3] = *(const bf16x8*)&LB[buf][ks][boff + 1536];                         \
    STAGE(sb, sk, skt, 1);                                                    \
    asm volatile("s_barrier" ::: "memory");                                   \
    __builtin_amdgcn_s_setprio(1);                                            \
    _Pragma("unroll") for (int m_ = 0; m_ < 8; ++m_) {                        \
      acc[m_][2] = MFMA_(a[m_], b[2], acc[m_][2], 0, 0, 0);                   \
      acc[m_][3] = MFMA_(a[m_], b[3], acc[m_][3], 0, 0, 0);                   \
    }                                                                         \
    __builtin_amdgcn_s_setprio(0);                                            \
    asm volatile("s_waitcnt vmcnt(8)");                                       \
    asm volatile("s_barrier" ::: "memory");                                   \
  }

  const int NT = K >> 6;

  STAGE(0, 0, 0, 0); STAGE(0, 0, 0, 1);
  STAGE(0, 1, 0, 0); STAGE(0, 1, 0, 1);
  STAGE(1, 0, 1, 0); STAGE(1, 0, 1, 1);
  asm volatile("s_waitcnt vmcnt(8)");
  asm volatile("s_barrier" ::: "memory");

  for (int i = 0; i < (NT >> 1); ++i) {
    const int kt0 = 2 * i;
    const int ktA = (kt0 + 2 < NT) ? kt0 + 2 : NT - 1;
    const int ktB = (kt0 + 3 < NT) ? kt0 + 3 : NT - 1;
    PHASE_EVEN(0, 0, 1, 1, kt0 + 1)
    PHASE_ODD (0, 0, 1, 1, kt0 + 1)
    PHASE_EVEN(0, 1, 0, 0, ktA)
    PHASE_ODD (0, 1, 0, 0, ktA)
    PHASE_EVEN(1, 0, 0, 1, ktA)
    PHASE_ODD (1, 0, 0, 1, ktA)
    PHASE_EVEN(1, 1, 1, 0, ktB)
    PHASE_ODD (1, 1, 1, 0, ktB)
  }
#undef PHASE_EVEN
#undef PHASE_ODD
#undef STAGE

  const int crow0 = m0 + wr * 128 + l4 * 4;
  const int ccol0 = n0 + wc * 64 + l15;
#pragma unroll
  for (int m_ = 0; m_ < 8; ++m_)
#pragma unroll
    for (int n_ = 0; n_ < 4; ++n_)
#pragma unroll
      for (int r_ = 0; r_ < 4; ++r_) {
        const size_t row = crow0 + m_ * 16 + r_;
        const int col = ccol0 + n_ * 16;
        const float val = acc[m_][n_][r_];
        if (OUT_BF16) ((ushort*)Cp)[row * N + col] = f2bf(val);
        else          ((float*)Cp)[row * N + col]  = val;
      }
}

// ---------------------------------------------------------------------------
// RoPE for Q and K in one launch. hp 0-31 = Q head (scaled), 32-39 = K head.
// ---------------------------------------------------------------------------
__global__ __launch_bounds__(256)
void rope_qk_kernel(ushort* qkv, const int* __restrict__ pos_ids, int total) {
  int t = blockIdx.x * 256 + threadIdx.x;
  if (t >= total) return;
  int j = t & 63;
  int rest = t >> 6;
  int hp = rest % 40;
  int bs = rest / 40;
  float pos = (float)pos_ids[bs];
  float inv = exp2f(-(float)j * (13.287712379549449f / 64.0f));
  float ang = pos * inv;
  const float osc = (hp < 32) ? 0.12751731f : 1.0f;   // Q: 1/sqrt(128)*log2e
  float c = cosf(ang) * osc, s = sinf(ang) * osc;
  const int col = (hp < 32) ? hp * HD : HIDDEN + (hp - 32) * HD;
  ushort* p = qkv + (size_t)bs * QKVLD + col + j;
  float x1 = bf2f(p[0]), x2 = bf2f(p[64]);
  p[0]  = f2bf(x1 * c - x2 * s);
  p[64] = f2bf(x2 * c + x1 * s);
}

// ---------------------------------------------------------------------------
// Flash attention, causal, GQA. 8 warps x 32 q-rows (block = 256 q x 1 head).
// Swapped QK^T (32x32x16), in-register P (cvt_pk + permlane32_swap),
// O^T = mfma(V^T, P^T), scalar softmax state per lane.
// R14: 4-buffer K/V pipeline — stage tiles t+2,t+3 (2-ahead), compute t and
// t+1, ONE barrier per 2 tiles. Buffers written are 2-ahead: their readers
// (tile t-2) finished at the previous iteration's barrier. nt % 4 == 0 always.
// Dynamic LDS 128 KB: Ks[4] 16KB each + Vs[4] 16KB each.
// ---------------------------------------------------------------------------
__global__ __launch_bounds__(512)
void attn_kernel(const ushort* __restrict__ Q, const ushort* __restrict__ K0,
                 const ushort* __restrict__ VtG, ushort* __restrict__ AO) {
  extern __shared__ ushort alds[];      // 128 KB
  ushort* Ks[4];
  ushort* Vs[4];
#pragma unroll
  for (int i = 0; i < 4; ++i) {
    Ks[i] = alds + i * 8192;            // [k][d], slot16 ^= (k&15)
    Vs[i] = alds + 32768 + i * 8192;    // [d][k], slot8  ^= (d&7)
  }

  const int bid = blockIdx.x;
  const int kh  = bid & 7;
  const int r2  = bid >> 3;
  const int qtB = 7 - (r2 & 7);         // LPT
  const int hq  = (r2 >> 3) & 3;
  const int b   = r2 >> 5;
  const int h   = kh * 4 + hq;
  const int q0b = qtB * 256;

  const int tid = threadIdx.x, lane = tid & 63, w = tid >> 6;
  const int l31 = lane & 31, hi = lane >> 5;
  const int q0w = q0b + w * 32;

  const size_t bS = (size_t)b * SEQ;
  const ushort* Kb = K0 + bS * QKVLD + kh * HD;
  const ushort* Vb = VtG + (size_t)(b * NKV + kh) * HD * SEQ;

  bf16x8 qf[8];
  {
    const ushort* qp = Q + (bS + q0w + l31) * QKVLD + h * HD + hi * 8;
#pragma unroll
    for (int ds = 0; ds < 8; ++ds) qf[ds] = *(const bf16x8*)(qp + ds * 16);
  }

  f32x16 accO[4] = {};
  float mrow = -1e30f, denom = 0.0f;

  const int nt = qtB * 4 + 4;           // multiple of 4

  const int j0 = 2 * w, j1 = 2 * w + 1;
  const int kl4 = lane >> 4, ks15 = lane & 15;
  const int vl3 = lane >> 3, vs7 = lane & 7;
  const int kswz = lane & 15;
  const int vswz = lane & 7;

#define KSTAGE(jj, bb, kk0) { const int k_ = (jj) * 4 + kl4;                   \
    gload_lds16(Kb + (size_t)((kk0) + k_) * QKVLD + ((ks15 ^ (k_ & 15)) << 3), \
                &Ks[bb][(jj) * 512 + lane * 8]); }
#define VSTAGE(jj, bb, kk0) { const int d_ = (jj) * 8 + vl3;                   \
    gload_lds16(Vb + (size_t)d_ * SEQ + (kk0) + ((vs7 ^ (d_ & 7)) << 3),       \
                &Vs[bb][(jj) * 512 + lane * 8]); }

  // prologue: stage tiles 0 and 1 (nt >= 4 always)
  KSTAGE(j0, 0, 0)  KSTAGE(j1, 0, 0)  VSTAGE(j0, 0, 0)  VSTAGE(j1, 0, 0)
  KSTAGE(j0, 1, 64) KSTAGE(j1, 1, 64) VSTAGE(j0, 1, 64) VSTAGE(j1, 1, 64)
  __syncthreads();

  for (int t = 0; t < nt; t += 2) {
    // ---- stage tiles t+2, t+3 (2-ahead; readers done at prev barrier) ----
    if (t + 2 < nt) {
      const int bb = (t + 2) & 3, kk = (t + 2) * 64;
      KSTAGE(j0, bb, kk) KSTAGE(j1, bb, kk) VSTAGE(j0, bb, kk) VSTAGE(j1, bb, kk)
    }
    if (t + 3 < nt) {
      const int bb = (t + 3) & 3, kk = (t + 3) * 64;
      KSTAGE(j0, bb, kk) KSTAGE(j1, bb, kk) VSTAGE(j0, bb, kk) VSTAGE(j1, bb, kk)
    }

    // ---- compute tiles t and t+1 ----
#pragma unroll
    for (int u = 0; u < 2; ++u) {
      const int tt = t + u;
      const int k0 = tt * 64;
      const int cb = tt & 3;
      if (k0 > q0w + 31) continue;      // fully masked for this warp

      f32x16 s0 = {}, s1 = {};
      __builtin_amdgcn_s_setprio(1);
#pragma unroll
      for (int ds = 0; ds < 8; ++ds) {
        const int so = ((ds * 2 + hi) ^ kswz) << 3;
        bf16x8 kf0 = *(const bf16x8*)&Ks[cb][l31 * 128 + so];
        bf16x8 kf1 = *(const bf16x8*)&Ks[cb][(32 + l31) * 128 + so];
        s0 = __builtin_amdgcn_mfma_f32_32x32x16_bf16(kf0, qf[ds], s0, 0, 0, 0);
        s1 = __builtin_amdgcn_mfma_f32_32x32x16_bf16(kf1, qf[ds], s1, 0, 0, 0);
      }
      __builtin_amdgcn_s_setprio(0);

      if (k0 + 63 > q0w) {
        const int qrel = q0w + l31 - k0;
#pragma unroll
        for (int r = 0; r < 16; ++r) {
          const int kc = (r & 3) + 8 * (r >> 2) + 4 * hi;
          if (kc > qrel)      s0[r] = -1e30f;
          if (kc + 32 > qrel) s1[r] = -1e30f;
        }
      }
      float pm = s0[0];
#pragma unroll
      for (int r = 1; r < 16; ++r) pm = fmaxf(pm, s0[r]);
#pragma unroll
      for (int r = 0; r < 16; ++r) pm = fmaxf(pm, s1[r]);

      if (!__all(pm - mrow <= 8.0f)) {
        pm = fmaxf(pm, __shfl_xor(pm, 32));
        const float mn = fmaxf(mrow, pm);
        const float alpha = exp2f(mrow - mn);
        mrow = mn;
        denom *= alpha;
#pragma unroll
        for (int du = 0; du < 4; ++du)
#pragma unroll
          for (int r = 0; r < 16; ++r) accO[du][r] *= alpha;
      }
      float ssum = 0.0f;
#pragma unroll
      for (int r = 0; r < 16; ++r) { float p = exp2f(s0[r] - mrow); s0[r] = p; ssum += p; }
#pragma unroll
      for (int r = 0; r < 16; ++r) { float p = exp2f(s1[r] - mrow); s1[r] = p; ssum += p; }
      denom += ssum;

      uint32_t paw[4][4];
      {
        uint32_t p0 = cvtpk(s0[0], s0[1]),   p1 = cvtpk(s0[2], s0[3]);
        uint32_t p2 = cvtpk(s0[4], s0[5]),   p3 = cvtpk(s0[6], s0[7]);
        uint32_t p4 = cvtpk(s0[8], s0[9]),   p5 = cvtpk(s0[10], s0[11]);
        uint32_t p6 = cvtpk(s0[12], s0[13]), p7 = cvtpk(s0[14], s0[15]);
        pl32swap(p0, p2); pl32swap(p1, p3); pl32swap(p4, p6); pl32swap(p5, p7);
        paw[0][0] = p0; paw[0][1] = p1; paw[0][2] = p2; paw[0][3] = p3;
        paw[1][0] = p4; paw[1][1] = p5; paw[1][2] = p6; paw[1][3] = p7;
      }
      {
        uint32_t p0 = cvtpk(s1[0], s1[1]),   p1 = cvtpk(s1[2], s1[3]);
        uint32_t p2 = cvtpk(s1[4], s1[5]),   p3 = cvtpk(s1[6], s1[7]);
        uint32_t p4 = cvtpk(s1[8], s1[9]),   p5 = cvtpk(s1[10], s1[11]);
        uint32_t p6 = cvtpk(s1[12], s1[13]), p7 = cvtpk(s1[14], s1[15]);
        pl32swap(p0, p2); pl32swap(p1, p3); pl32swap(p4, p6); pl32swap(p5, p7);
        paw[2][0] = p0; paw[2][1] = p1; paw[2][2] = p2; paw[2][3] = p3;
        paw[3][0] = p4; paw[3][1] = p5; paw[3][2] = p6; paw[3][3] = p7;
      }

      __builtin_amdgcn_s_setprio(1);
#pragma unroll
      for (int du = 0; du < 4; ++du) {
#pragma unroll
        for (int ks = 0; ks < 4; ++ks) {
          const int so = ((ks * 2 + hi) ^ vswz) << 3;
          bf16x8 vf = *(const bf16x8*)&Vs[cb][(du * 32 + l31) * 64 + so];
          bf16x8 pb = *(const bf16x8*)&paw[ks][0];
          accO[du] = __builtin_amdgcn_mfma_f32_32x32x16_bf16(vf, pb, accO[du], 0, 0, 0);
        }
      }
      __builtin_amdgcn_s_setprio(0);
    }
    __syncthreads();   // drains t+2/t+3 staging; closes reads of bufs t, t+1
  }
#undef KSTAGE
#undef VSTAGE

  denom += __shfl_xor(denom, 32);
  const float inv = 1.0f / denom;
  ushort* op = AO + (bS + q0w + l31) * HIDDEN + h * HD + hi * 4;
#pragma unroll
  for (int du = 0; du < 4; ++du)
#pragma unroll
    for (int g = 0; g < 4; ++g) {
      uint2 u;
      u.x = cvtpk(accO[du][4 * g + 0] * inv, accO[du][4 * g + 1] * inv);
      u.y = cvtpk(accO[du][4 * g + 2] * inv, accO[du][4 * g + 3] * inv);
      *(uint2*)(op + du * 32 + g * 8) = u;
    }
}

// ---------------------------------------------------------------------------
extern "C" void kernel_launch(void* const* d_in, const int* in_sizes, int n_in,
                              void* d_out, int out_size, void* d_ws, size_t ws_size,
                              hipStream_t stream) {
  (void)in_sizes; (void)n_in; (void)out_size; (void)ws_size;
  const float* X   = (const float*)d_in[0];
  const int*   pos = (const int*)d_in[2];
  const float* Wq  = (const float*)d_in[3];
  const float* Wk  = (const float*)d_in[4];
  const float* Wv  = (const float*)d_in[5];
  const float* Wo  = (const float*)d_in[6];

  char* ws = (char*)d_ws;
  ushort* Xb    = (ushort*)(ws);                    // 33,554,432 B (aliased by AO)
  ushort* QKV   = (ushort*)(ws + 33554432);         // 50,331,648 B  [M][6144]
  ushort* BTqkv = (ushort*)(ws + 83886080);         // 50,331,648 B
  ushort* WoT   = (ushort*)(ws + 134217728);        // 33,554,432 B
  ushort* AO    = Xb;                               // X dead after QKV projection
  ushort* VtG   = BTqkv;                            // BTqkv dead after QKV GEMM

  const int M = BSZ * SEQ;  // 4096
  dim3 blk(256);

  hipFuncSetAttribute((const void*)gemmqkv_kernel,
                      hipFuncAttributeMaxDynamicSharedMemorySize, 114688);
  hipFuncSetAttribute((const void*)gemm8p_kernel<0>,
                      hipFuncAttributeMaxDynamicSharedMemorySize, 131072);
  hipFuncSetAttribute((const void*)attn_kernel,
                      hipFuncAttributeMaxDynamicSharedMemorySize, 131072);

  // ---- pre-passes: X convert + all 4 weight transposes in one launch ----
  cvt_bf16_kernel<<<dim3((M * HIDDEN / 8 + 255) / 256), blk, 0, stream>>>(X, Xb, M * HIDDEN / 8);
  transpose_all_kernel<<<dim3(10240), blk, 0, stream>>>(Wq, Wk, Wv, Wo, BTqkv, WoT);

  // ---- fused QKV projection: 256x192 tiles -> 512 blocks ----
  gemmqkv_kernel<<<dim3((M / 256) * (QKVN / 192)), dim3(512), 114688, stream>>>(
      Xb, BTqkv, QKV, M, QKVN, HIDDEN);

  // ---- RoPE Q+K in one launch + V transpose ----
  rope_qk_kernel<<<dim3((M * 40 * 64) / 256), blk, 0, stream>>>(QKV, pos, M * 40 * 64);
  transpose_v_kernel<<<dim3(SEQ / 64, HD / 64, BSZ * NKV), blk, 0, stream>>>(
      QKV + HIDDEN + NKV * HD, VtG);

  // ---- flash attention: 4-buffer 2-tiles-per-barrier pipeline ----
  attn_kernel<<<dim3(512), dim3(512), 131072, stream>>>(QKV, QKV + HIDDEN, VtG, AO);

  // ---- output projection -> fp32 d_out (R11 gemm8p restored) ----
  gemm8p_kernel<0><<<dim3((M / 256) * (HIDDEN / 256)), dim3(512), 131072, stream>>>(
      AO, WoT, d_out, M, HIDDEN, HIDDEN);
}